// Round 5
// baseline (119.042 us; speedup 1.0000x reference)
//
#include <hip/hip_runtime.h>
#include <hip/hip_bf16.h>

// out[e] = dot(ufeat[src[e]], ifeat[dst[e]]), D=256 fp32, E=300K.
//
// r3 finding: gather is EA-bytes-bound (~3.4 TB/s past-L2 rate, FETCH 133MB).
// r4: confine each dst-slice (6250 rows = 3.2MB fp16 < 4MiB per-XCD L2) to one
// XCD. Grid is replicated x8 over chunks; block b (intended XCD b%8) processes
// only edges in its chunk with dst/6250 == b%8. Coverage is exact regardless of
// the real block->XCD mapping (locality heuristic only). dst checks use
// wave-uniform broadcast loads; src loaded only on group match.

typedef _Float16 half4 __attribute__((ext_vector_type(4)));
typedef _Float16 half8 __attribute__((ext_vector_type(8)));
typedef float    f32x4 __attribute__((ext_vector_type(4)));

// ---------------- conversion: fp32 tables -> fp16 in workspace ----------------
__global__ __launch_bounds__(256) void cvt_f32_to_f16(
    const float* __restrict__ u, const float* __restrict__ v,
    _Float16* __restrict__ uh, _Float16* __restrict__ vh,
    int nU, int nTotal)
{
    int i = blockIdx.x * blockDim.x + threadIdx.x;
    const int stride = gridDim.x * blockDim.x;
    const int total8 = nTotal / 8;
    for (; i < total8; i += stride) {
        const int j = i * 8;
        const float* sp;
        _Float16* dp;
        if (j < nU) { sp = u + j;        dp = uh + j; }
        else        { sp = v + (j - nU); dp = vh + (j - nU); }
        // non-temporal reads: the fp32 source is dead after this pass; keep it
        // from evicting the fp16 tables the gather is about to read.
        const f32x4 f0 = __builtin_nontemporal_load(reinterpret_cast<const f32x4*>(sp));
        const f32x4 f1 = __builtin_nontemporal_load(reinterpret_cast<const f32x4*>(sp) + 1);
        half8 h;
        h[0] = (_Float16)f0.x; h[1] = (_Float16)f0.y;
        h[2] = (_Float16)f0.z; h[3] = (_Float16)f0.w;
        h[4] = (_Float16)f1.x; h[5] = (_Float16)f1.y;
        h[6] = (_Float16)f1.z; h[7] = (_Float16)f1.w;
        *reinterpret_cast<half8*>(dp) = h;
    }
}

// ---------------- per-edge gather-dot helper ----------------
__device__ __forceinline__ void dot_one(
    const _Float16* __restrict__ uh, const _Float16* __restrict__ vh,
    int s, int t, float* __restrict__ out, int e, int lane, size_t lo)
{
    const half4 a = *reinterpret_cast<const half4*>(uh + (size_t)s * 256 + lo);
    const half4 b = *reinterpret_cast<const half4*>(vh + (size_t)t * 256 + lo);
    float u = 0.f;
    #pragma unroll
    for (int k = 0; k < 4; ++k) u += (float)a[k] * (float)b[k];
    #pragma unroll
    for (int off = 32; off > 0; off >>= 1) u += __shfl_xor(u, off, 64);
    if (lane == 0) out[e] = u;
}

// ---------------- dst-bucketed fp16 gather-dot ----------------
// grid = nChunks * 8; block b: chunk = b>>3, bucket = b&7.
// chunk covers 128 edges (4 waves x 32); wave processes its 32 edges in
// int4-groups, skipping groups with no dst in this block's bucket.
__global__ __launch_bounds__(256) void edge_dot_f16_bucketed(
    const _Float16* __restrict__ uh,
    const _Float16* __restrict__ vh,
    const int* __restrict__ src,
    const int* __restrict__ dst,
    float* __restrict__ out,
    int E, unsigned rowsPerBucket)
{
    const unsigned bucket = blockIdx.x & 7;
    const int chunk = blockIdx.x >> 3;
    const int wave  = threadIdx.x >> 6;
    const int lane  = threadIdx.x & 63;
    const size_t lo = (size_t)lane * 4;

    const int base = chunk * 128 + wave * 32;
    if (base >= E) return;
    const int lim = min(base + 32, E);

    for (int e4 = base; e4 < lim; e4 += 4) {
        if (e4 + 3 < E) {
            // wave-uniform broadcast load of 4 dst indices
            const int4 tv = *reinterpret_cast<const int4*>(dst + e4);
            const bool m0 = ((unsigned)tv.x / rowsPerBucket) == bucket;
            const bool m1 = ((unsigned)tv.y / rowsPerBucket) == bucket;
            const bool m2 = ((unsigned)tv.z / rowsPerBucket) == bucket;
            const bool m3 = ((unsigned)tv.w / rowsPerBucket) == bucket;
            if (!(m0 | m1 | m2 | m3)) continue;
            const int4 sv = *reinterpret_cast<const int4*>(src + e4);
            if (m0) dot_one(uh, vh, sv.x, tv.x, out, e4 + 0, lane, lo);
            if (m1) dot_one(uh, vh, sv.y, tv.y, out, e4 + 1, lane, lo);
            if (m2) dot_one(uh, vh, sv.z, tv.z, out, e4 + 2, lane, lo);
            if (m3) dot_one(uh, vh, sv.w, tv.w, out, e4 + 3, lane, lo);
        } else {
            for (int e = e4; e < lim; ++e) {
                const int t = dst[e];
                if (((unsigned)t / rowsPerBucket) != bucket) continue;
                dot_one(uh, vh, src[e], t, out, e, lane, lo);
            }
        }
    }
}

// ---------------- fp32 fallback if ws too small ----------------
__global__ __launch_bounds__(256) void edge_dot_f32(
    const float* __restrict__ ufeat,
    const float* __restrict__ ifeat,
    const int* __restrict__ src,
    const int* __restrict__ dst,
    float* __restrict__ out,
    int E)
{
    const int wid  = (blockIdx.x * blockDim.x + threadIdx.x) >> 6;
    const int lane = threadIdx.x & 63;
    const int e0   = wid * 4;
    if (e0 >= E) return;
    const size_t lo = (size_t)lane * 4;

    for (int e = e0; e < min(e0 + 4, E); ++e) {
        const float4 a = *reinterpret_cast<const float4*>(ufeat + (size_t)src[e] * 256 + lo);
        const float4 b = *reinterpret_cast<const float4*>(ifeat + (size_t)dst[e] * 256 + lo);
        float u = a.x*b.x + a.y*b.y + a.z*b.z + a.w*b.w;
        #pragma unroll
        for (int off = 32; off > 0; off >>= 1) u += __shfl_xor(u, off, 64);
        if (lane == 0) out[e] = u;
    }
}

extern "C" void kernel_launch(void* const* d_in, const int* in_sizes, int n_in,
                              void* d_out, int out_size, void* d_ws, size_t ws_size,
                              hipStream_t stream)
{
    const float* ufeat = (const float*)d_in[0];   // (20000, 256) f32
    const float* ifeat = (const float*)d_in[1];   // (50000, 256) f32
    const int*   src   = (const int*)d_in[2];     // (E,) i32
    const int*   dst   = (const int*)d_in[3];     // (E,) i32
    float*       out   = (float*)d_out;           // (E, 1) f32

    const int E     = in_sizes[2];
    const int nU    = in_sizes[0];                // 5,120,000
    const int nV    = in_sizes[1];                // 12,800,000
    const int nCell = nV / 256;                   // 50,000 rows
    const size_t needBytes = (size_t)(nU + nV) * sizeof(_Float16);

    const int block = 256;

    if (ws_size >= needBytes) {
        _Float16* uh = (_Float16*)d_ws;
        _Float16* vh = uh + nU;

        cvt_f32_to_f16<<<2048, block, 0, stream>>>(ufeat, ifeat, uh, vh,
                                                   nU, nU + nV);

        // 8 dst-buckets, one per XCD; slice = rowsPerBucket*512B (~3.2MB) < 4MiB L2
        const unsigned rowsPerBucket = (unsigned)((nCell + 7) / 8);   // 6250
        const int nChunks = (E + 127) / 128;
        edge_dot_f16_bucketed<<<nChunks * 8, block, 0, stream>>>(
            uh, vh, src, dst, out, E, rowsPerBucket);
    } else {
        const int edgesPerBlock = (block / 64) * 4;
        const int grid = (E + edgesPerBlock - 1) / edgesPerBlock;
        edge_dot_f32<<<grid, block, 0, stream>>>(ufeat, ifeat, src, dst, out, E);
    }
}

// Round 6
// 64.336 us; speedup vs baseline: 1.8503x; 1.8503x over previous
//
#include <hip/hip_runtime.h>
#include <hip/hip_bf16.h>

// out[e] = dot(ufeat[src[e]], ifeat[dst[e]]), D=256 fp32, E=300K.
//
// Findings r1-r5: gather time = FETCH / ~3.4 TB/s (fixed EA/L2-miss rate;
// MLP-insensitive). FETCH floor for any dst-partitioned schedule is ~100MB
// (u-side compulsory ~70MB across 8 private L2s + v 25.6MB + idx), so the
// unsorted fp16 gather at 133MB is within ~25% of the byte floor; a 2-key
// sort would cost about what it saves. r5's scan-based bucketing regressed
// (VALU-bound). This is the r3 structure: fp16 cvt pre-pass + 4-edge/wave
// fp16 gather-dot. NT loads in cvt keep the dead fp32 source from evicting
// the fp16 tables the gather is about to read.

typedef _Float16 half4 __attribute__((ext_vector_type(4)));
typedef _Float16 half8 __attribute__((ext_vector_type(8)));
typedef float    f32x4 __attribute__((ext_vector_type(4)));

// ---------------- conversion: fp32 tables -> fp16 in workspace ----------------
__global__ __launch_bounds__(256) void cvt_f32_to_f16(
    const float* __restrict__ u, const float* __restrict__ v,
    _Float16* __restrict__ uh, _Float16* __restrict__ vh,
    int nU, int nTotal)
{
    int i = blockIdx.x * blockDim.x + threadIdx.x;
    const int stride = gridDim.x * blockDim.x;
    const int total8 = nTotal / 8;
    for (; i < total8; i += stride) {
        const int j = i * 8;
        const float* sp;
        _Float16* dp;
        if (j < nU) { sp = u + j;        dp = uh + j; }
        else        { sp = v + (j - nU); dp = vh + (j - nU); }
        const f32x4 f0 = __builtin_nontemporal_load(reinterpret_cast<const f32x4*>(sp));
        const f32x4 f1 = __builtin_nontemporal_load(reinterpret_cast<const f32x4*>(sp) + 1);
        half8 h;
        h[0] = (_Float16)f0.x; h[1] = (_Float16)f0.y;
        h[2] = (_Float16)f0.z; h[3] = (_Float16)f0.w;
        h[4] = (_Float16)f1.x; h[5] = (_Float16)f1.y;
        h[6] = (_Float16)f1.z; h[7] = (_Float16)f1.w;
        *reinterpret_cast<half8*>(dp) = h;
    }
}

// ---------------- fp16 gather-dot: 4 edges per wave ----------------
__global__ __launch_bounds__(256) void edge_dot_f16(
    const _Float16* __restrict__ uh,
    const _Float16* __restrict__ vh,
    const int* __restrict__ src,
    const int* __restrict__ dst,
    float* __restrict__ out,
    int E)
{
    const int wid  = (blockIdx.x * blockDim.x + threadIdx.x) >> 6;
    const int lane = threadIdx.x & 63;
    const int e0   = wid * 4;
    if (e0 >= E) return;

    const size_t lo = (size_t)lane * 4;   // element offset within row

    if (e0 + 3 < E) {
        const int4 sv = *reinterpret_cast<const int4*>(src + e0);
        const int4 tv = *reinterpret_cast<const int4*>(dst + e0);

        // 8 independent 8B gathers in flight
        const half4 a0 = *reinterpret_cast<const half4*>(uh + (size_t)sv.x * 256 + lo);
        const half4 b0 = *reinterpret_cast<const half4*>(vh + (size_t)tv.x * 256 + lo);
        const half4 a1 = *reinterpret_cast<const half4*>(uh + (size_t)sv.y * 256 + lo);
        const half4 b1 = *reinterpret_cast<const half4*>(vh + (size_t)tv.y * 256 + lo);
        const half4 a2 = *reinterpret_cast<const half4*>(uh + (size_t)sv.z * 256 + lo);
        const half4 b2 = *reinterpret_cast<const half4*>(vh + (size_t)tv.z * 256 + lo);
        const half4 a3 = *reinterpret_cast<const half4*>(uh + (size_t)sv.w * 256 + lo);
        const half4 b3 = *reinterpret_cast<const half4*>(vh + (size_t)tv.w * 256 + lo);

        float u0 = 0.f, u1 = 0.f, u2 = 0.f, u3 = 0.f;
        #pragma unroll
        for (int k = 0; k < 4; ++k) {
            u0 += (float)a0[k] * (float)b0[k];
            u1 += (float)a1[k] * (float)b1[k];
            u2 += (float)a2[k] * (float)b2[k];
            u3 += (float)a3[k] * (float)b3[k];
        }

        #pragma unroll
        for (int off = 32; off > 0; off >>= 1) {
            u0 += __shfl_xor(u0, off, 64);
            u1 += __shfl_xor(u1, off, 64);
            u2 += __shfl_xor(u2, off, 64);
            u3 += __shfl_xor(u3, off, 64);
        }

        float v = u0;
        v = (lane == 1) ? u1 : v;
        v = (lane == 2) ? u2 : v;
        v = (lane == 3) ? u3 : v;
        if (lane < 4) out[e0 + lane] = v;
    } else {
        for (int e = e0; e < E; ++e) {
            const half4 a = *reinterpret_cast<const half4*>(uh + (size_t)src[e] * 256 + lo);
            const half4 b = *reinterpret_cast<const half4*>(vh + (size_t)dst[e] * 256 + lo);
            float u = 0.f;
            #pragma unroll
            for (int k = 0; k < 4; ++k) u += (float)a[k] * (float)b[k];
            #pragma unroll
            for (int off = 32; off > 0; off >>= 1) u += __shfl_xor(u, off, 64);
            if (lane == 0) out[e] = u;
        }
    }
}

// ---------------- fp32 fallback if ws too small ----------------
__global__ __launch_bounds__(256) void edge_dot_f32(
    const float* __restrict__ ufeat,
    const float* __restrict__ ifeat,
    const int* __restrict__ src,
    const int* __restrict__ dst,
    float* __restrict__ out,
    int E)
{
    const int wid  = (blockIdx.x * blockDim.x + threadIdx.x) >> 6;
    const int lane = threadIdx.x & 63;
    const int e0   = wid * 4;
    if (e0 >= E) return;
    const size_t lo = (size_t)lane * 4;

    for (int e = e0; e < min(e0 + 4, E); ++e) {
        const float4 a = *reinterpret_cast<const float4*>(ufeat + (size_t)src[e] * 256 + lo);
        const float4 b = *reinterpret_cast<const float4*>(ifeat + (size_t)dst[e] * 256 + lo);
        float u = a.x*b.x + a.y*b.y + a.z*b.z + a.w*b.w;
        #pragma unroll
        for (int off = 32; off > 0; off >>= 1) u += __shfl_xor(u, off, 64);
        if (lane == 0) out[e] = u;
    }
}

extern "C" void kernel_launch(void* const* d_in, const int* in_sizes, int n_in,
                              void* d_out, int out_size, void* d_ws, size_t ws_size,
                              hipStream_t stream)
{
    const float* ufeat = (const float*)d_in[0];   // (20000, 256) f32
    const float* ifeat = (const float*)d_in[1];   // (50000, 256) f32
    const int*   src   = (const int*)d_in[2];     // (E,) i32
    const int*   dst   = (const int*)d_in[3];     // (E,) i32
    float*       out   = (float*)d_out;           // (E, 1) f32

    const int E  = in_sizes[2];
    const int nU = in_sizes[0];                   // 5,120,000
    const int nV = in_sizes[1];                   // 12,800,000
    const size_t needBytes = (size_t)(nU + nV) * sizeof(_Float16);  // 35.84 MB

    const int block = 256;
    const int edgesPerBlock = (block / 64) * 4;   // 16 edges/block
    const int grid = (E + edgesPerBlock - 1) / edgesPerBlock;

    if (ws_size >= needBytes) {
        _Float16* uh = (_Float16*)d_ws;
        _Float16* vh = uh + nU;

        cvt_f32_to_f16<<<2048, block, 0, stream>>>(ufeat, ifeat, uh, vh,
                                                   nU, nU + nV);
        edge_dot_f16<<<grid, block, 0, stream>>>(uh, vh, src, dst, out, E);
    } else {
        edge_dot_f32<<<grid, block, 0, stream>>>(ufeat, ifeat, src, dst, out, E);
    }
}

// Round 7
// 60.399 us; speedup vs baseline: 1.9709x; 1.0652x over previous
//
#include <hip/hip_runtime.h>
#include <hip/hip_bf16.h>

// out[e] = dot(ufeat[src[e]], ifeat[dst[e]]), D=256 fp32, E=300K.
//
// Findings r1-r6:
//  - gather time = FETCH / ~3.45 TB/s (past-L2/fabric rate; MLP-invariant (r2),
//    bytes-proportional (r3/r6)). FETCH=133MB is ~25% above the locality floor;
//    closing that gap (sort/bucketing) costs about what it saves (r5).
//  - cvt pass (107MB read + 36MB write) runs at streaming floor ~21us.
//  - NT loads in cvt REGRESSED 3.6us (r6): the fp32 source was L2/L3-resident
//    across replays; NT pushed it back to HBM. Reverted to plain loads.
//  - fp16 is the precision floor (fp8 error model exceeds the 1.75 threshold).
// This is the r3 kernel exactly: fp16 cvt pre-pass + 4-edge/wave gather-dot.

typedef _Float16 half4 __attribute__((ext_vector_type(4)));
typedef _Float16 half8 __attribute__((ext_vector_type(8)));

// ---------------- conversion: fp32 tables -> fp16 in workspace ----------------
__global__ __launch_bounds__(256) void cvt_f32_to_f16(
    const float* __restrict__ u, const float* __restrict__ v,
    _Float16* __restrict__ uh, _Float16* __restrict__ vh,
    int nU, int nTotal)
{
    int i = blockIdx.x * blockDim.x + threadIdx.x;
    const int stride = gridDim.x * blockDim.x;
    const int total8 = nTotal / 8;
    for (; i < total8; i += stride) {
        const int j = i * 8;
        const float* sp;
        _Float16* dp;
        if (j < nU) { sp = u + j;        dp = uh + j; }
        else        { sp = v + (j - nU); dp = vh + (j - nU); }
        const float4 f0 = *reinterpret_cast<const float4*>(sp);
        const float4 f1 = *reinterpret_cast<const float4*>(sp + 4);
        half8 h;
        h[0] = (_Float16)f0.x; h[1] = (_Float16)f0.y;
        h[2] = (_Float16)f0.z; h[3] = (_Float16)f0.w;
        h[4] = (_Float16)f1.x; h[5] = (_Float16)f1.y;
        h[6] = (_Float16)f1.z; h[7] = (_Float16)f1.w;
        *reinterpret_cast<half8*>(dp) = h;
    }
}

// ---------------- fp16 gather-dot: 4 edges per wave ----------------
__global__ __launch_bounds__(256) void edge_dot_f16(
    const _Float16* __restrict__ uh,
    const _Float16* __restrict__ vh,
    const int* __restrict__ src,
    const int* __restrict__ dst,
    float* __restrict__ out,
    int E)
{
    const int wid  = (blockIdx.x * blockDim.x + threadIdx.x) >> 6;
    const int lane = threadIdx.x & 63;
    const int e0   = wid * 4;
    if (e0 >= E) return;

    const size_t lo = (size_t)lane * 4;   // element offset within row

    if (e0 + 3 < E) {
        const int4 sv = *reinterpret_cast<const int4*>(src + e0);
        const int4 tv = *reinterpret_cast<const int4*>(dst + e0);

        // 8 independent 8B gathers in flight
        const half4 a0 = *reinterpret_cast<const half4*>(uh + (size_t)sv.x * 256 + lo);
        const half4 b0 = *reinterpret_cast<const half4*>(vh + (size_t)tv.x * 256 + lo);
        const half4 a1 = *reinterpret_cast<const half4*>(uh + (size_t)sv.y * 256 + lo);
        const half4 b1 = *reinterpret_cast<const half4*>(vh + (size_t)tv.y * 256 + lo);
        const half4 a2 = *reinterpret_cast<const half4*>(uh + (size_t)sv.z * 256 + lo);
        const half4 b2 = *reinterpret_cast<const half4*>(vh + (size_t)tv.z * 256 + lo);
        const half4 a3 = *reinterpret_cast<const half4*>(uh + (size_t)sv.w * 256 + lo);
        const half4 b3 = *reinterpret_cast<const half4*>(vh + (size_t)tv.w * 256 + lo);

        float u0 = 0.f, u1 = 0.f, u2 = 0.f, u3 = 0.f;
        #pragma unroll
        for (int k = 0; k < 4; ++k) {
            u0 += (float)a0[k] * (float)b0[k];
            u1 += (float)a1[k] * (float)b1[k];
            u2 += (float)a2[k] * (float)b2[k];
            u3 += (float)a3[k] * (float)b3[k];
        }

        #pragma unroll
        for (int off = 32; off > 0; off >>= 1) {
            u0 += __shfl_xor(u0, off, 64);
            u1 += __shfl_xor(u1, off, 64);
            u2 += __shfl_xor(u2, off, 64);
            u3 += __shfl_xor(u3, off, 64);
        }

        float v = u0;
        v = (lane == 1) ? u1 : v;
        v = (lane == 2) ? u2 : v;
        v = (lane == 3) ? u3 : v;
        if (lane < 4) out[e0 + lane] = v;
    } else {
        for (int e = e0; e < E; ++e) {
            const half4 a = *reinterpret_cast<const half4*>(uh + (size_t)src[e] * 256 + lo);
            const half4 b = *reinterpret_cast<const half4*>(vh + (size_t)dst[e] * 256 + lo);
            float u = 0.f;
            #pragma unroll
            for (int k = 0; k < 4; ++k) u += (float)a[k] * (float)b[k];
            #pragma unroll
            for (int off = 32; off > 0; off >>= 1) u += __shfl_xor(u, off, 64);
            if (lane == 0) out[e] = u;
        }
    }
}

// ---------------- fp32 fallback if ws too small ----------------
__global__ __launch_bounds__(256) void edge_dot_f32(
    const float* __restrict__ ufeat,
    const float* __restrict__ ifeat,
    const int* __restrict__ src,
    const int* __restrict__ dst,
    float* __restrict__ out,
    int E)
{
    const int wid  = (blockIdx.x * blockDim.x + threadIdx.x) >> 6;
    const int lane = threadIdx.x & 63;
    const int e0   = wid * 4;
    if (e0 >= E) return;
    const size_t lo = (size_t)lane * 4;

    for (int e = e0; e < min(e0 + 4, E); ++e) {
        const float4 a = *reinterpret_cast<const float4*>(ufeat + (size_t)src[e] * 256 + lo);
        const float4 b = *reinterpret_cast<const float4*>(ifeat + (size_t)dst[e] * 256 + lo);
        float u = a.x*b.x + a.y*b.y + a.z*b.z + a.w*b.w;
        #pragma unroll
        for (int off = 32; off > 0; off >>= 1) u += __shfl_xor(u, off, 64);
        if (lane == 0) out[e] = u;
    }
}

extern "C" void kernel_launch(void* const* d_in, const int* in_sizes, int n_in,
                              void* d_out, int out_size, void* d_ws, size_t ws_size,
                              hipStream_t stream)
{
    const float* ufeat = (const float*)d_in[0];   // (20000, 256) f32
    const float* ifeat = (const float*)d_in[1];   // (50000, 256) f32
    const int*   src   = (const int*)d_in[2];     // (E,) i32
    const int*   dst   = (const int*)d_in[3];     // (E,) i32
    float*       out   = (float*)d_out;           // (E, 1) f32

    const int E  = in_sizes[2];
    const int nU = in_sizes[0];                   // 5,120,000
    const int nV = in_sizes[1];                   // 12,800,000
    const size_t needBytes = (size_t)(nU + nV) * sizeof(_Float16);  // 35.84 MB

    const int block = 256;
    const int edgesPerBlock = (block / 64) * 4;   // 16 edges/block
    const int grid = (E + edgesPerBlock - 1) / edgesPerBlock;

    if (ws_size >= needBytes) {
        _Float16* uh = (_Float16*)d_ws;
        _Float16* vh = uh + nU;

        cvt_f32_to_f16<<<2048, block, 0, stream>>>(ufeat, ifeat, uh, vh,
                                                   nU, nU + nV);
        edge_dot_f16<<<grid, block, 0, stream>>>(uh, vh, src, dst, out, E);
    } else {
        edge_dot_f32<<<grid, block, 0, stream>>>(ufeat, ifeat, src, dst, out, E);
    }
}